// Round 4
// baseline (580.498 us; speedup 1.0000x reference)
//
#include <hip/hip_runtime.h>
#include <hip/hip_bf16.h>

// Problem constants
#define BB 64
#define NN 4096
#define DD 64
#define HH 256
#define SS 1024
#define TOTAL 49152          // 3*D*H
#define MAT_ELEMS 16384      // D*H

typedef __bf16 bf16x8 __attribute__((ext_vector_type(8)));
typedef float  f32x4  __attribute__((ext_vector_type(4)));

// ---------------------------------------------------------------------------
// K0: convert s[64][1024] fp32 -> fragment-ordered bf16 hi/lo for K1's MFMA
// A-operand. Output index ((ks*4+mf)*64 + lane)*8 + j holds
// s[mf*16 + (lane&15)][ks*32 + (lane>>4)*8 + j], so K1's A-load is one
// coalesced bf16x8 per lane. hi = rne(s), lo = rne(s - hi)  (|err| ~ 2^-18).
// ---------------------------------------------------------------------------
__global__ __launch_bounds__(256) void k0_sconv(
    const float* __restrict__ s, __bf16* __restrict__ sHi, __bf16* __restrict__ sLo)
{
    const int idx  = blockIdx.x * 256 + threadIdx.x;   // 8192 = 32ks * 4mf * 64lane
    const int lane = idx & 63;
    const int fs   = idx >> 6;
    const int mf   = fs & 3;
    const int ks   = fs >> 2;
    const int m = mf * 16 + (lane & 15);
    const int k = ks * 32 + (lane >> 4) * 8;
    const float* sp = &s[(size_t)m * SS + k];
    float4 v0 = *(const float4*)(sp);
    float4 v1 = *(const float4*)(sp + 4);
    float vv[8] = {v0.x, v0.y, v0.z, v0.w, v1.x, v1.y, v1.z, v1.w};
    bf16x8 hi, lo;
    #pragma unroll
    for (int j = 0; j < 8; j++) {
        __bf16 h = (__bf16)vv[j];
        hi[j] = h;
        lo[j] = (__bf16)(vv[j] - (float)h);
    }
    *(bf16x8*)&sHi[(size_t)idx * 8] = hi;
    *(bf16x8*)&sLo[(size_t)idx * 8] = lo;
}

// ---------------------------------------------------------------------------
// K1 v4: params[64][49152] = s @ W_pg + b_pg via split-bf16 MFMA.
// Same as v3 but DOUBLE-BUFFERED LDS: one barrier per K-step instead of two
// (the 2-barrier structure pays the full stage+drain stall twice per 12
// MFMAs). Write buf[k&1]; barrier; compute buf[k&1]; next iter writes
// buf[k&1^1] -- cross-wave safety: reads of buf[p] at iter k-1 precede
// barrier_k, writes of buf[p] at iter k+1 follow it.
// Block: 64m x 64n, 4 waves, full K=1024, grid 768 = 3 blocks/CU.
// LDS 2*8448 = 16896 B. VGPR ~90, no spill risk.
// ---------------------------------------------------------------------------
__global__ __launch_bounds__(256, 3) void k1_gemm(
    const __bf16* __restrict__ sHi, const __bf16* __restrict__ sLo,
    const float* __restrict__ W, const float* __restrict__ bias,
    float* __restrict__ params)
{
    const int n0   = blockIdx.x * 64;
    const int t    = threadIdx.x;
    const int w    = t >> 6;
    const int lane = t & 63;
    const int l15  = lane & 15;
    const int quad = lane >> 4;
    const int wn   = w * 16;

    __shared__ float sW[2][32 * 66];    // [buf][kk][n] fp32, pad 66

    f32x4 acc[4] = {};                  // mf = 0..3 -> m = mf*16 + quad*4 + r

    // staging map: 256 threads x 8 floats = 32x64 tile
    const int srow = t >> 3;            // kk 0..31
    const int scol = (t & 7) * 8;       // n within tile
    const float* wp = &W[(size_t)srow * TOTAL + n0 + scol];

    float4 p0 = *(const float4*)(wp);
    float4 p1 = *(const float4*)(wp + 4);

    for (int ks = 0; ks < 32; ks++) {
        float* buf = sW[ks & 1];
        *(float4*)&buf[srow * 66 + scol]     = p0;
        *(float4*)&buf[srow * 66 + scol + 4] = p1;
        __syncthreads();
        if (ks < 31) {                  // prefetch next K-step under compute
            const float* wpn = wp + (size_t)(ks + 1) * 32 * TOTAL;
            p0 = *(const float4*)(wpn);
            p1 = *(const float4*)(wpn + 4);
        }
        // B-fragment: col = wn + l15, k = quad*8 + j; convert fp32 -> hi/lo
        bf16x8 bHi, bLo;
        #pragma unroll
        for (int j = 0; j < 8; j++) {
            float v  = buf[(quad * 8 + j) * 66 + wn + l15];
            __bf16 h = (__bf16)v;
            bHi[j] = h;
            bLo[j] = (__bf16)(v - (float)h);
        }
        // A-fragments: fragment-ordered, one bf16x8 per lane per mf
        const __bf16* ah = &sHi[((size_t)(ks * 4) * 64 + lane) * 8];
        const __bf16* al = &sLo[((size_t)(ks * 4) * 64 + lane) * 8];
        #pragma unroll
        for (int mf = 0; mf < 4; mf++) {
            bf16x8 aHi = *(const bf16x8*)(ah + mf * 512);
            bf16x8 aLo = *(const bf16x8*)(al + mf * 512);
            acc[mf] = __builtin_amdgcn_mfma_f32_16x16x32_bf16(aHi, bHi, acc[mf], 0, 0, 0);
            acc[mf] = __builtin_amdgcn_mfma_f32_16x16x32_bf16(aHi, bLo, acc[mf], 0, 0, 0);
            acc[mf] = __builtin_amdgcn_mfma_f32_16x16x32_bf16(aLo, bHi, acc[mf], 0, 0, 0);
        }
        // no trailing barrier: next iteration writes the other buffer
    }

    // epilogue: C/D layout col = l15, row = quad*4 + r; add bias, store fp32
    const int n = n0 + wn + l15;
    const float bv = bias[n];
    #pragma unroll
    for (int mf = 0; mf < 4; mf++) {
        #pragma unroll
        for (int r = 0; r < 4; r++) {
            int m = mf * 16 + quad * 4 + r;
            params[(size_t)m * TOTAL + n] = acc[mf][r] + bv;
        }
    }
}

// ---------------------------------------------------------------------------
// K2a v3: fc1 gate/value l2norm along D (64), write transposed bf16 WT[h][d].
// Single params read (bias already added by K1). grid 1024, block 256.
// ---------------------------------------------------------------------------
__global__ __launch_bounds__(256) void k2_fc1(
    const float* __restrict__ params, __bf16* __restrict__ WgT, __bf16* __restrict__ WvT)
{
    const int b    = blockIdx.x >> 4;
    const int mat  = (blockIdx.x >> 3) & 1;
    const int hg   = blockIdx.x & 7;
    const int t    = threadIdx.x;
    const int hh   = t & 31;        // h within group of 32
    const int dseg = t >> 5;        // 0..7, covers d = dseg*8..+7
    const int h    = hg * 32 + hh;

    __shared__ float psum[8 * 32];
    __shared__ float rnorm[32];

    const float* p0 = params + (size_t)b * TOTAL + mat * MAT_ELEMS;

    float val[8];
    float ss = 0.f;
    #pragma unroll
    for (int j = 0; j < 8; j++) {
        int off = (dseg * 8 + j) * 256 + h;
        float v = p0[off];
        val[j] = v;
        ss += v * v;
    }
    psum[dseg * 32 + hh] = ss;
    __syncthreads();
    if (t < 32) {
        float s2 = 0.f;
        #pragma unroll
        for (int g = 0; g < 8; g++) s2 += psum[g * 32 + t];
        rnorm[t] = 1.0f / fmaxf(sqrtf(s2), 1e-12f);
    }
    __syncthreads();
    float rn = rnorm[hh];
    __bf16* dst = (mat ? WvT : WgT) + (size_t)b * MAT_ELEMS + (size_t)h * 64 + dseg * 8;
    bf16x8 ov;
    #pragma unroll
    for (int j = 0; j < 8; j++) ov[j] = (__bf16)(val[j] * rn);
    *(bf16x8*)dst = ov;
}

// ---------------------------------------------------------------------------
// K2b v3: fc2 l2norm along H (256), write transposed bf16 WfT[d][h].
// Single params read. grid 512, block 256.
// ---------------------------------------------------------------------------
__global__ __launch_bounds__(256) void k2_fc2(
    const float* __restrict__ params, __bf16* __restrict__ WfT)
{
    const int b    = blockIdx.x >> 3;
    const int dg   = blockIdx.x & 7;
    const int t    = threadIdx.x;
    const int dd   = t & 7;         // d within group of 8
    const int hseg = t >> 3;        // 0..31, covers h = hseg*8..+7

    __shared__ float psum[32 * 8];
    __shared__ float rnorm[8];

    const float* p0 = params + (size_t)b * TOTAL + 2 * MAT_ELEMS;

    float val[8];
    float ss = 0.f;
    #pragma unroll
    for (int j = 0; j < 8; j++) {
        int off = (hseg * 8 + j) * 64 + dg * 8 + dd;
        float v = p0[off];
        val[j] = v;
        ss += v * v;
    }
    psum[hseg * 8 + dd] = ss;
    __syncthreads();
    if (t < 8) {
        float s2 = 0.f;
        #pragma unroll
        for (int g = 0; g < 32; g++) s2 += psum[g * 8 + t];
        rnorm[t] = 1.0f / fmaxf(sqrtf(s2), 1e-12f);
    }
    __syncthreads();
    float rn = rnorm[dd];
    __bf16* dst = WfT + (size_t)b * MAT_ELEMS + (size_t)(dg * 8 + dd) * 256 + hseg * 8;
    bf16x8 ov;
    #pragma unroll
    for (int j = 0; j < 8; j++) ov[j] = (__bf16)(val[j] * rn);
    *(bf16x8*)dst = ov;
}

// ---------------------------------------------------------------------------
// K3 v3: fused  xn = rmsnorm(x)*scale;  g = xn@Wg; v = xn@Wv; h = silu(g)*v;
//            out = h@Wf + x.
// Counters (r3): MfmaUtil 8.4 / VALUBusy 19 / HBM 16.5 / Occ 40, VGPR 56 ->
// latency-bound at 4 waves/SIMD, LDS-capped. Restructure half(128h) ->
// QUARTER(64h) granularity: fc1 2 iters then fc2 2 sweeps, x4. hbuf shrinks
// [32][136] -> [32][72] bf16 per wave = 18432 B/block -> 8 blocks/CU
// (= 2048-thread cap, 8 waves/SIMD, 2x latency hiding). launch_bounds
// (256,8) caps VGPR at 64 (measured 56). Same index algebra; read pattern
// stays 2-way bank-aliased (free). NO __syncthreads anywhere.
// ---------------------------------------------------------------------------
__global__ __launch_bounds__(256, 8) void k3_fused(
    const float* __restrict__ x, const float* __restrict__ scale,
    const __bf16* __restrict__ WgT, const __bf16* __restrict__ WvT,
    const __bf16* __restrict__ WfT, float* __restrict__ out)
{
    const int b    = blockIdx.x >> 5;
    const int rb   = blockIdx.x & 31;
    const int t    = threadIdx.x;
    const int w    = t >> 6;
    const int lane = t & 63;
    const int l15  = lane & 15;
    const int quad = lane >> 4;

    __shared__ __bf16 h_sh[4 * 32 * 72];    // 18432 B: per-wave [32 rows][64h pad 72]

    const size_t row_base = ((size_t)b * NN + rb * 128) * DD;

    // per-lane scale slices for k = quad*8+j and 32+quad*8+j
    float sc[16];
    *(float4*)&sc[0]  = *(const float4*)&scale[quad * 8];
    *(float4*)&sc[4]  = *(const float4*)&scale[quad * 8 + 4];
    *(float4*)&sc[8]  = *(const float4*)&scale[32 + quad * 8];
    *(float4*)&sc[12] = *(const float4*)&scale[32 + quad * 8 + 4];

    // ---- phase 0: build A-fragments straight from global ----
    bf16x8 afrag[2][2];
    #pragma unroll
    for (int mt = 0; mt < 2; mt++) {
        int row = w * 32 + mt * 16 + l15;
        const float* xp = &x[row_base + (size_t)row * DD + quad * 8];
        float v[16];
        *(float4*)&v[0]  = *(const float4*)(xp);
        *(float4*)&v[4]  = *(const float4*)(xp + 4);
        *(float4*)&v[8]  = *(const float4*)(xp + 32);
        *(float4*)&v[12] = *(const float4*)(xp + 36);
        float ss = 0.f;
        #pragma unroll
        for (int j = 0; j < 16; j++) ss += v[j] * v[j];
        ss += __shfl_xor(ss, 16, 64);
        ss += __shfl_xor(ss, 32, 64);
        float rr = rsqrtf(ss * (1.0f / 64.0f) + 1e-6f);
        #pragma unroll
        for (int j = 0; j < 8; j++) {
            afrag[mt][0][j] = (__bf16)(v[j] * rr * sc[j]);
            afrag[mt][1][j] = (__bf16)(v[8 + j] * rr * sc[8 + j]);
        }
    }

    f32x4 oacc[2][4] = {};   // [mt][dt]
    const __bf16* wg_b = WgT + (size_t)b * MAT_ELEMS;
    const __bf16* wv_b = WvT + (size_t)b * MAT_ELEMS;
    const __bf16* wf_b = WfT + (size_t)b * MAT_ELEMS;
    __bf16* hbuf = &h_sh[w * 32 * 72];

    for (int qtr = 0; qtr < 4; qtr++) {
        // ============ fc1 phase: 2 np iterations, write-only LDS ===========
        #pragma unroll
        for (int npl = 0; npl < 2; npl++) {
            const int np = qtr * 2 + npl;
            // batch-issue all 8 weight fragment loads
            bf16x8 bg[2][2], bv[2][2];
            #pragma unroll
            for (int sub = 0; sub < 2; sub++) {
                int nt = np * 2 + sub;
                const __bf16* gp = &wg_b[(nt * 16 + l15) * 64 + quad * 8];
                const __bf16* vp = &wv_b[(nt * 16 + l15) * 64 + quad * 8];
                bg[sub][0] = *(const bf16x8*)(gp);
                bg[sub][1] = *(const bf16x8*)(gp + 32);
                bv[sub][0] = *(const bf16x8*)(vp);
                bv[sub][1] = *(const bf16x8*)(vp + 32);
            }
            #pragma unroll
            for (int sub = 0; sub < 2; sub++) {
                #pragma unroll
                for (int mt = 0; mt < 2; mt++) {
                    f32x4 g = {0.f, 0.f, 0.f, 0.f}, vv = {0.f, 0.f, 0.f, 0.f};
                    g  = __builtin_amdgcn_mfma_f32_16x16x32_bf16(afrag[mt][0], bg[sub][0], g, 0, 0, 0);
                    g  = __builtin_amdgcn_mfma_f32_16x16x32_bf16(afrag[mt][1], bg[sub][1], g, 0, 0, 0);
                    vv = __builtin_amdgcn_mfma_f32_16x16x32_bf16(afrag[mt][0], bv[sub][0], vv, 0, 0, 0);
                    vv = __builtin_amdgcn_mfma_f32_16x16x32_bf16(afrag[mt][1], bv[sub][1], vv, 0, 0, 0);
                    #pragma unroll
                    for (int r = 0; r < 4; r++) {
                        float gv = g[r];
                        float sig = __builtin_amdgcn_rcpf(1.0f + __expf(-gv));
                        float hval = gv * sig * vv[r];
                        hbuf[(mt * 16 + quad * 4 + r) * 72 + npl * 32 + sub * 16 + l15] = (__bf16)hval;
                    }
                }
            }
        }
        // ============ fc2 phase: sweep the 64-h quarter ====================
        #pragma unroll
        for (int kpl = 0; kpl < 2; kpl++) {
            const int kp = qtr * 2 + kpl;
            bf16x8 bf[4];
            #pragma unroll
            for (int dt = 0; dt < 4; dt++)
                bf[dt] = *(const bf16x8*)&wf_b[(dt * 16 + l15) * 256 + kp * 32 + quad * 8];
            #pragma unroll
            for (int mt = 0; mt < 2; mt++) {
                bf16x8 ah = *(const bf16x8*)&hbuf[(mt * 16 + l15) * 72 + kpl * 32 + quad * 8];
                #pragma unroll
                for (int dt = 0; dt < 4; dt++)
                    oacc[mt][dt] = __builtin_amdgcn_mfma_f32_16x16x32_bf16(ah, bf[dt], oacc[mt][dt], 0, 0, 0);
            }
        }
    }

    // ---- epilogue: += x residual (cache-hot), store fp32 (C-layout) ----
    #pragma unroll
    for (int mt = 0; mt < 2; mt++) {
        int r0 = w * 32 + mt * 16 + quad * 4;
        #pragma unroll
        for (int rg = 0; rg < 4; rg++) {
            size_t roff = row_base + (size_t)(r0 + rg) * DD;
            #pragma unroll
            for (int dt = 0; dt < 4; dt++) {
                int col = dt * 16 + l15;
                out[roff + col] = oacc[mt][dt][rg] + x[roff + col];
            }
        }
    }
}

// ---------------------------------------------------------------------------
extern "C" void kernel_launch(void* const* d_in, const int* in_sizes, int n_in,
                              void* d_out, int out_size, void* d_ws, size_t ws_size,
                              hipStream_t stream)
{
    const float* x     = (const float*)d_in[0];
    const float* s     = (const float*)d_in[1];
    const float* W_pg  = (const float*)d_in[2];
    const float* b_pg  = (const float*)d_in[3];
    const float* scale = (const float*)d_in[4];
    float* out = (float*)d_out;

    char* ws = (char*)d_ws;
    float*  params = (float*)ws;                                  // 12,582,912 B
    __bf16* WgT    = (__bf16*)(ws + 12582912);                    //  2,097,152 B
    __bf16* WvT    = (__bf16*)(ws + 14680064);                    //  2,097,152 B
    __bf16* WfT    = (__bf16*)(ws + 16777216);                    //  2,097,152 B
    __bf16* sHi    = (__bf16*)(ws + 18874368);                    //    131,072 B
    __bf16* sLo    = (__bf16*)(ws + 19005440);                    //    131,072 B

    k0_sconv<<<32, 256, 0, stream>>>(s, sHi, sLo);
    k1_gemm<<<TOTAL / 64, 256, 0, stream>>>(sHi, sLo, W_pg, b_pg, params);
    k2_fc1<<<BB * 16, 256, 0, stream>>>(params, WgT, WvT);
    k2_fc2<<<BB * 8, 256, 0, stream>>>(params, WfT);
    k3_fused<<<BB * 32, 256, 0, stream>>>(x, scale, WgT, WvT, WfT, out);
}

// Round 5
// 505.531 us; speedup vs baseline: 1.1483x; 1.1483x over previous
//
#include <hip/hip_runtime.h>
#include <hip/hip_bf16.h>

// Problem constants
#define BB 64
#define NN 4096
#define DD 64
#define HH 256
#define SS 1024
#define TOTAL 49152          // 3*D*H
#define MAT_ELEMS 16384      // D*H

typedef __bf16 bf16x8 __attribute__((ext_vector_type(8)));
typedef float  f32x4  __attribute__((ext_vector_type(4)));

// ---------------------------------------------------------------------------
// K0: convert s[64][1024] fp32 -> fragment-ordered bf16 hi/lo for K1's MFMA
// A-operand. Output index ((ks*4+mf)*64 + lane)*8 + j holds
// s[mf*16 + (lane&15)][ks*32 + (lane>>4)*8 + j], so K1's A-load is one
// coalesced bf16x8 per lane. hi = rne(s), lo = rne(s - hi)  (|err| ~ 2^-18).
// ---------------------------------------------------------------------------
__global__ __launch_bounds__(256) void k0_sconv(
    const float* __restrict__ s, __bf16* __restrict__ sHi, __bf16* __restrict__ sLo)
{
    const int idx  = blockIdx.x * 256 + threadIdx.x;   // 8192 = 32ks * 4mf * 64lane
    const int lane = idx & 63;
    const int fs   = idx >> 6;
    const int mf   = fs & 3;
    const int ks   = fs >> 2;
    const int m = mf * 16 + (lane & 15);
    const int k = ks * 32 + (lane >> 4) * 8;
    const float* sp = &s[(size_t)m * SS + k];
    float4 v0 = *(const float4*)(sp);
    float4 v1 = *(const float4*)(sp + 4);
    float vv[8] = {v0.x, v0.y, v0.z, v0.w, v1.x, v1.y, v1.z, v1.w};
    bf16x8 hi, lo;
    #pragma unroll
    for (int j = 0; j < 8; j++) {
        __bf16 h = (__bf16)vv[j];
        hi[j] = h;
        lo[j] = (__bf16)(vv[j] - (float)h);
    }
    *(bf16x8*)&sHi[(size_t)idx * 8] = hi;
    *(bf16x8*)&sLo[(size_t)idx * 8] = lo;
}

// ---------------------------------------------------------------------------
// K1 v4: params[64][49152] = s @ W_pg + b_pg via split-bf16 MFMA.
// Double-buffered LDS: one barrier per K-step. Write buf[k&1]; barrier;
// compute buf[k&1]; next iter writes buf[k&1^1] (cross-wave safe: reads of
// buf[p] at iter k-1 precede barrier_k, writes of buf[p] at iter k+1 follow).
// Block: 64m x 64n, 4 waves, full K=1024, grid 768 = 3 blocks/CU.
// LDS 2*8448 = 16896 B. VGPR ~90, no spill risk.
// ---------------------------------------------------------------------------
__global__ __launch_bounds__(256, 3) void k1_gemm(
    const __bf16* __restrict__ sHi, const __bf16* __restrict__ sLo,
    const float* __restrict__ W, const float* __restrict__ bias,
    float* __restrict__ params)
{
    const int n0   = blockIdx.x * 64;
    const int t    = threadIdx.x;
    const int w    = t >> 6;
    const int lane = t & 63;
    const int l15  = lane & 15;
    const int quad = lane >> 4;
    const int wn   = w * 16;

    __shared__ float sW[2][32 * 66];    // [buf][kk][n] fp32, pad 66

    f32x4 acc[4] = {};                  // mf = 0..3 -> m = mf*16 + quad*4 + r

    // staging map: 256 threads x 8 floats = 32x64 tile
    const int srow = t >> 3;            // kk 0..31
    const int scol = (t & 7) * 8;       // n within tile
    const float* wp = &W[(size_t)srow * TOTAL + n0 + scol];

    float4 p0 = *(const float4*)(wp);
    float4 p1 = *(const float4*)(wp + 4);

    for (int ks = 0; ks < 32; ks++) {
        float* buf = sW[ks & 1];
        *(float4*)&buf[srow * 66 + scol]     = p0;
        *(float4*)&buf[srow * 66 + scol + 4] = p1;
        __syncthreads();
        if (ks < 31) {                  // prefetch next K-step under compute
            const float* wpn = wp + (size_t)(ks + 1) * 32 * TOTAL;
            p0 = *(const float4*)(wpn);
            p1 = *(const float4*)(wpn + 4);
        }
        // B-fragment: col = wn + l15, k = quad*8 + j; convert fp32 -> hi/lo
        bf16x8 bHi, bLo;
        #pragma unroll
        for (int j = 0; j < 8; j++) {
            float v  = buf[(quad * 8 + j) * 66 + wn + l15];
            __bf16 h = (__bf16)v;
            bHi[j] = h;
            bLo[j] = (__bf16)(v - (float)h);
        }
        // A-fragments: fragment-ordered, one bf16x8 per lane per mf
        const __bf16* ah = &sHi[((size_t)(ks * 4) * 64 + lane) * 8];
        const __bf16* al = &sLo[((size_t)(ks * 4) * 64 + lane) * 8];
        #pragma unroll
        for (int mf = 0; mf < 4; mf++) {
            bf16x8 aHi = *(const bf16x8*)(ah + mf * 512);
            bf16x8 aLo = *(const bf16x8*)(al + mf * 512);
            acc[mf] = __builtin_amdgcn_mfma_f32_16x16x32_bf16(aHi, bHi, acc[mf], 0, 0, 0);
            acc[mf] = __builtin_amdgcn_mfma_f32_16x16x32_bf16(aHi, bLo, acc[mf], 0, 0, 0);
            acc[mf] = __builtin_amdgcn_mfma_f32_16x16x32_bf16(aLo, bHi, acc[mf], 0, 0, 0);
        }
        // no trailing barrier: next iteration writes the other buffer
    }

    // epilogue: C/D layout col = l15, row = quad*4 + r; add bias, store fp32
    const int n = n0 + wn + l15;
    const float bv = bias[n];
    #pragma unroll
    for (int mf = 0; mf < 4; mf++) {
        #pragma unroll
        for (int r = 0; r < 4; r++) {
            int m = mf * 16 + quad * 4 + r;
            params[(size_t)m * TOTAL + n] = acc[mf][r] + bv;
        }
    }
}

// ---------------------------------------------------------------------------
// K2a v3: fc1 gate/value l2norm along D (64), write transposed bf16 WT[h][d].
// Single params read (bias already added by K1). grid 1024, block 256.
// ---------------------------------------------------------------------------
__global__ __launch_bounds__(256) void k2_fc1(
    const float* __restrict__ params, __bf16* __restrict__ WgT, __bf16* __restrict__ WvT)
{
    const int b    = blockIdx.x >> 4;
    const int mat  = (blockIdx.x >> 3) & 1;
    const int hg   = blockIdx.x & 7;
    const int t    = threadIdx.x;
    const int hh   = t & 31;        // h within group of 32
    const int dseg = t >> 5;        // 0..7, covers d = dseg*8..+7
    const int h    = hg * 32 + hh;

    __shared__ float psum[8 * 32];
    __shared__ float rnorm[32];

    const float* p0 = params + (size_t)b * TOTAL + mat * MAT_ELEMS;

    float val[8];
    float ss = 0.f;
    #pragma unroll
    for (int j = 0; j < 8; j++) {
        int off = (dseg * 8 + j) * 256 + h;
        float v = p0[off];
        val[j] = v;
        ss += v * v;
    }
    psum[dseg * 32 + hh] = ss;
    __syncthreads();
    if (t < 32) {
        float s2 = 0.f;
        #pragma unroll
        for (int g = 0; g < 8; g++) s2 += psum[g * 32 + t];
        rnorm[t] = 1.0f / fmaxf(sqrtf(s2), 1e-12f);
    }
    __syncthreads();
    float rn = rnorm[hh];
    __bf16* dst = (mat ? WvT : WgT) + (size_t)b * MAT_ELEMS + (size_t)h * 64 + dseg * 8;
    bf16x8 ov;
    #pragma unroll
    for (int j = 0; j < 8; j++) ov[j] = (__bf16)(val[j] * rn);
    *(bf16x8*)dst = ov;
}

// ---------------------------------------------------------------------------
// K2b v3: fc2 l2norm along H (256), write transposed bf16 WfT[d][h].
// Single params read. grid 512, block 256.
// ---------------------------------------------------------------------------
__global__ __launch_bounds__(256) void k2_fc2(
    const float* __restrict__ params, __bf16* __restrict__ WfT)
{
    const int b    = blockIdx.x >> 3;
    const int dg   = blockIdx.x & 7;
    const int t    = threadIdx.x;
    const int dd   = t & 7;         // d within group of 8
    const int hseg = t >> 3;        // 0..31, covers h = hseg*8..+7

    __shared__ float psum[32 * 8];
    __shared__ float rnorm[8];

    const float* p0 = params + (size_t)b * TOTAL + 2 * MAT_ELEMS;

    float val[8];
    float ss = 0.f;
    #pragma unroll
    for (int j = 0; j < 8; j++) {
        int off = (hseg * 8 + j) * 64 + dg * 8 + dd;
        float v = p0[off];
        val[j] = v;
        ss += v * v;
    }
    psum[hseg * 8 + dd] = ss;
    __syncthreads();
    if (t < 8) {
        float s2 = 0.f;
        #pragma unroll
        for (int g = 0; g < 32; g++) s2 += psum[g * 8 + t];
        rnorm[t] = 1.0f / fmaxf(sqrtf(s2), 1e-12f);
    }
    __syncthreads();
    float rn = rnorm[dd];
    __bf16* dst = WfT + (size_t)b * MAT_ELEMS + (size_t)(dg * 8 + dd) * 256 + hseg * 8;
    bf16x8 ov;
    #pragma unroll
    for (int j = 0; j < 8; j++) ov[j] = (__bf16)(val[j] * rn);
    *(bf16x8*)dst = ov;
}

// ---------------------------------------------------------------------------
// K3 v4: fused  xn = rmsnorm(x)*scale;  g = xn@Wg; v = xn@Wv; h = silu(g)*v;
//            out = h@Wf + x.
// Quarter(64h) granularity (r4 structure): hbuf [32][72] bf16 per wave =
// 18432 B/block -> LDS allows 8 blocks/CU.
// r4 POST-MORTEM: __launch_bounds__(256,8) forced a 64-reg total budget ->
// compiler spilled to scratch (VGPR 56->32, hbm_bytes 160->880 MB, dur
// 120->258 us). FIX: bound (256,6) = 85-reg budget >> 56 natural alloc ->
// no spill; HW can still schedule up to 8 waves/SIMD since 56 <= 64.
// Same index algebra; reads 2-way bank-aliased (free). NO __syncthreads.
// ---------------------------------------------------------------------------
__global__ __launch_bounds__(256, 6) void k3_fused(
    const float* __restrict__ x, const float* __restrict__ scale,
    const __bf16* __restrict__ WgT, const __bf16* __restrict__ WvT,
    const __bf16* __restrict__ WfT, float* __restrict__ out)
{
    const int b    = blockIdx.x >> 5;
    const int rb   = blockIdx.x & 31;
    const int t    = threadIdx.x;
    const int w    = t >> 6;
    const int lane = t & 63;
    const int l15  = lane & 15;
    const int quad = lane >> 4;

    __shared__ __bf16 h_sh[4 * 32 * 72];    // 18432 B: per-wave [32 rows][64h pad 72]

    const size_t row_base = ((size_t)b * NN + rb * 128) * DD;

    // per-lane scale slices for k = quad*8+j and 32+quad*8+j
    float sc[16];
    *(float4*)&sc[0]  = *(const float4*)&scale[quad * 8];
    *(float4*)&sc[4]  = *(const float4*)&scale[quad * 8 + 4];
    *(float4*)&sc[8]  = *(const float4*)&scale[32 + quad * 8];
    *(float4*)&sc[12] = *(const float4*)&scale[32 + quad * 8 + 4];

    // ---- phase 0: build A-fragments straight from global ----
    bf16x8 afrag[2][2];
    #pragma unroll
    for (int mt = 0; mt < 2; mt++) {
        int row = w * 32 + mt * 16 + l15;
        const float* xp = &x[row_base + (size_t)row * DD + quad * 8];
        float v[16];
        *(float4*)&v[0]  = *(const float4*)(xp);
        *(float4*)&v[4]  = *(const float4*)(xp + 4);
        *(float4*)&v[8]  = *(const float4*)(xp + 32);
        *(float4*)&v[12] = *(const float4*)(xp + 36);
        float ss = 0.f;
        #pragma unroll
        for (int j = 0; j < 16; j++) ss += v[j] * v[j];
        ss += __shfl_xor(ss, 16, 64);
        ss += __shfl_xor(ss, 32, 64);
        float rr = rsqrtf(ss * (1.0f / 64.0f) + 1e-6f);
        #pragma unroll
        for (int j = 0; j < 8; j++) {
            afrag[mt][0][j] = (__bf16)(v[j] * rr * sc[j]);
            afrag[mt][1][j] = (__bf16)(v[8 + j] * rr * sc[8 + j]);
        }
    }

    f32x4 oacc[2][4] = {};   // [mt][dt]
    const __bf16* wg_b = WgT + (size_t)b * MAT_ELEMS;
    const __bf16* wv_b = WvT + (size_t)b * MAT_ELEMS;
    const __bf16* wf_b = WfT + (size_t)b * MAT_ELEMS;
    __bf16* hbuf = &h_sh[w * 32 * 72];

    for (int qtr = 0; qtr < 4; qtr++) {
        // ============ fc1 phase: 2 np iterations, write-only LDS ===========
        #pragma unroll
        for (int npl = 0; npl < 2; npl++) {
            const int np = qtr * 2 + npl;
            // batch-issue all 8 weight fragment loads
            bf16x8 bg[2][2], bv[2][2];
            #pragma unroll
            for (int sub = 0; sub < 2; sub++) {
                int nt = np * 2 + sub;
                const __bf16* gp = &wg_b[(nt * 16 + l15) * 64 + quad * 8];
                const __bf16* vp = &wv_b[(nt * 16 + l15) * 64 + quad * 8];
                bg[sub][0] = *(const bf16x8*)(gp);
                bg[sub][1] = *(const bf16x8*)(gp + 32);
                bv[sub][0] = *(const bf16x8*)(vp);
                bv[sub][1] = *(const bf16x8*)(vp + 32);
            }
            #pragma unroll
            for (int sub = 0; sub < 2; sub++) {
                #pragma unroll
                for (int mt = 0; mt < 2; mt++) {
                    f32x4 g = {0.f, 0.f, 0.f, 0.f}, vv = {0.f, 0.f, 0.f, 0.f};
                    g  = __builtin_amdgcn_mfma_f32_16x16x32_bf16(afrag[mt][0], bg[sub][0], g, 0, 0, 0);
                    g  = __builtin_amdgcn_mfma_f32_16x16x32_bf16(afrag[mt][1], bg[sub][1], g, 0, 0, 0);
                    vv = __builtin_amdgcn_mfma_f32_16x16x32_bf16(afrag[mt][0], bv[sub][0], vv, 0, 0, 0);
                    vv = __builtin_amdgcn_mfma_f32_16x16x32_bf16(afrag[mt][1], bv[sub][1], vv, 0, 0, 0);
                    #pragma unroll
                    for (int r = 0; r < 4; r++) {
                        float gv = g[r];
                        float sig = __builtin_amdgcn_rcpf(1.0f + __expf(-gv));
                        float hval = gv * sig * vv[r];
                        hbuf[(mt * 16 + quad * 4 + r) * 72 + npl * 32 + sub * 16 + l15] = (__bf16)hval;
                    }
                }
            }
        }
        // ============ fc2 phase: sweep the 64-h quarter ====================
        #pragma unroll
        for (int kpl = 0; kpl < 2; kpl++) {
            const int kp = qtr * 2 + kpl;
            bf16x8 bf[4];
            #pragma unroll
            for (int dt = 0; dt < 4; dt++)
                bf[dt] = *(const bf16x8*)&wf_b[(dt * 16 + l15) * 256 + kp * 32 + quad * 8];
            #pragma unroll
            for (int mt = 0; mt < 2; mt++) {
                bf16x8 ah = *(const bf16x8*)&hbuf[(mt * 16 + l15) * 72 + kpl * 32 + quad * 8];
                #pragma unroll
                for (int dt = 0; dt < 4; dt++)
                    oacc[mt][dt] = __builtin_amdgcn_mfma_f32_16x16x32_bf16(ah, bf[dt], oacc[mt][dt], 0, 0, 0);
            }
        }
    }

    // ---- epilogue: += x residual (cache-hot), store fp32 (C-layout) ----
    #pragma unroll
    for (int mt = 0; mt < 2; mt++) {
        int r0 = w * 32 + mt * 16 + quad * 4;
        #pragma unroll
        for (int rg = 0; rg < 4; rg++) {
            size_t roff = row_base + (size_t)(r0 + rg) * DD;
            #pragma unroll
            for (int dt = 0; dt < 4; dt++) {
                int col = dt * 16 + l15;
                out[roff + col] = oacc[mt][dt][rg] + x[roff + col];
            }
        }
    }
}

// ---------------------------------------------------------------------------
extern "C" void kernel_launch(void* const* d_in, const int* in_sizes, int n_in,
                              void* d_out, int out_size, void* d_ws, size_t ws_size,
                              hipStream_t stream)
{
    const float* x     = (const float*)d_in[0];
    const float* s     = (const float*)d_in[1];
    const float* W_pg  = (const float*)d_in[2];
    const float* b_pg  = (const float*)d_in[3];
    const float* scale = (const float*)d_in[4];
    float* out = (float*)d_out;

    char* ws = (char*)d_ws;
    float*  params = (float*)ws;                                  // 12,582,912 B
    __bf16* WgT    = (__bf16*)(ws + 12582912);                    //  2,097,152 B
    __bf16* WvT    = (__bf16*)(ws + 14680064);                    //  2,097,152 B
    __bf16* WfT    = (__bf16*)(ws + 16777216);                    //  2,097,152 B
    __bf16* sHi    = (__bf16*)(ws + 18874368);                    //    131,072 B
    __bf16* sLo    = (__bf16*)(ws + 19005440);                    //    131,072 B

    k0_sconv<<<32, 256, 0, stream>>>(s, sHi, sLo);
    k1_gemm<<<TOTAL / 64, 256, 0, stream>>>(sHi, sLo, W_pg, b_pg, params);
    k2_fc1<<<BB * 16, 256, 0, stream>>>(params, WgT, WvT);
    k2_fc2<<<BB * 8, 256, 0, stream>>>(params, WfT);
    k3_fused<<<BB * 32, 256, 0, stream>>>(x, scale, WgT, WvT, WfT, out);
}

// Round 6
// 441.411 us; speedup vs baseline: 1.3151x; 1.1453x over previous
//
#include <hip/hip_runtime.h>
#include <hip/hip_bf16.h>

// Problem constants
#define BB 64
#define NN 4096
#define DD 64
#define HH 256
#define SS 1024
#define TOTAL 49152          // 3*D*H
#define MAT_ELEMS 16384      // D*H

typedef __bf16 bf16x8 __attribute__((ext_vector_type(8)));
typedef float  f32x4  __attribute__((ext_vector_type(4)));

// ---------------------------------------------------------------------------
// K0: convert s[64][1024] fp32 -> fragment-ordered bf16 hi/lo for K1's MFMA
// A-operand. Output index ((ks*4+mf)*64 + lane)*8 + j holds
// s[mf*16 + (lane&15)][ks*32 + (lane>>4)*8 + j], so K1's A-load is one
// coalesced bf16x8 per lane. hi = rne(s), lo = rne(s - hi)  (|err| ~ 2^-18).
// ---------------------------------------------------------------------------
__global__ __launch_bounds__(256) void k0_sconv(
    const float* __restrict__ s, __bf16* __restrict__ sHi, __bf16* __restrict__ sLo)
{
    const int idx  = blockIdx.x * 256 + threadIdx.x;   // 8192 = 32ks * 4mf * 64lane
    const int lane = idx & 63;
    const int fs   = idx >> 6;
    const int mf   = fs & 3;
    const int ks   = fs >> 2;
    const int m = mf * 16 + (lane & 15);
    const int k = ks * 32 + (lane >> 4) * 8;
    const float* sp = &s[(size_t)m * SS + k];
    float4 v0 = *(const float4*)(sp);
    float4 v1 = *(const float4*)(sp + 4);
    float vv[8] = {v0.x, v0.y, v0.z, v0.w, v1.x, v1.y, v1.z, v1.w};
    bf16x8 hi, lo;
    #pragma unroll
    for (int j = 0; j < 8; j++) {
        __bf16 h = (__bf16)vv[j];
        hi[j] = h;
        lo[j] = (__bf16)(vv[j] - (float)h);
    }
    *(bf16x8*)&sHi[(size_t)idx * 8] = hi;
    *(bf16x8*)&sLo[(size_t)idx * 8] = lo;
}

// ---------------------------------------------------------------------------
// K1 v4: params[64][49152] = s @ W_pg + b_pg via split-bf16 MFMA.
// Double-buffered LDS: one barrier per K-step. Write buf[k&1]; barrier;
// compute buf[k&1]; next iter writes buf[k&1^1] (cross-wave safe: reads of
// buf[p] at iter k-1 precede barrier_k, writes of buf[p] at iter k+1 follow).
// Block: 64m x 64n, 4 waves, full K=1024, grid 768 = 3 blocks/CU.
// LDS 2*8448 = 16896 B. VGPR ~90, no spill risk.
// ---------------------------------------------------------------------------
__global__ __launch_bounds__(256, 3) void k1_gemm(
    const __bf16* __restrict__ sHi, const __bf16* __restrict__ sLo,
    const float* __restrict__ W, const float* __restrict__ bias,
    float* __restrict__ params)
{
    const int n0   = blockIdx.x * 64;
    const int t    = threadIdx.x;
    const int w    = t >> 6;
    const int lane = t & 63;
    const int l15  = lane & 15;
    const int quad = lane >> 4;
    const int wn   = w * 16;

    __shared__ float sW[2][32 * 66];    // [buf][kk][n] fp32, pad 66

    f32x4 acc[4] = {};                  // mf = 0..3 -> m = mf*16 + quad*4 + r

    // staging map: 256 threads x 8 floats = 32x64 tile
    const int srow = t >> 3;            // kk 0..31
    const int scol = (t & 7) * 8;       // n within tile
    const float* wp = &W[(size_t)srow * TOTAL + n0 + scol];

    float4 p0 = *(const float4*)(wp);
    float4 p1 = *(const float4*)(wp + 4);

    for (int ks = 0; ks < 32; ks++) {
        float* buf = sW[ks & 1];
        *(float4*)&buf[srow * 66 + scol]     = p0;
        *(float4*)&buf[srow * 66 + scol + 4] = p1;
        __syncthreads();
        if (ks < 31) {                  // prefetch next K-step under compute
            const float* wpn = wp + (size_t)(ks + 1) * 32 * TOTAL;
            p0 = *(const float4*)(wpn);
            p1 = *(const float4*)(wpn + 4);
        }
        // B-fragment: col = wn + l15, k = quad*8 + j; convert fp32 -> hi/lo
        bf16x8 bHi, bLo;
        #pragma unroll
        for (int j = 0; j < 8; j++) {
            float v  = buf[(quad * 8 + j) * 66 + wn + l15];
            __bf16 h = (__bf16)v;
            bHi[j] = h;
            bLo[j] = (__bf16)(v - (float)h);
        }
        // A-fragments: fragment-ordered, one bf16x8 per lane per mf
        const __bf16* ah = &sHi[((size_t)(ks * 4) * 64 + lane) * 8];
        const __bf16* al = &sLo[((size_t)(ks * 4) * 64 + lane) * 8];
        #pragma unroll
        for (int mf = 0; mf < 4; mf++) {
            bf16x8 aHi = *(const bf16x8*)(ah + mf * 512);
            bf16x8 aLo = *(const bf16x8*)(al + mf * 512);
            acc[mf] = __builtin_amdgcn_mfma_f32_16x16x32_bf16(aHi, bHi, acc[mf], 0, 0, 0);
            acc[mf] = __builtin_amdgcn_mfma_f32_16x16x32_bf16(aHi, bLo, acc[mf], 0, 0, 0);
            acc[mf] = __builtin_amdgcn_mfma_f32_16x16x32_bf16(aLo, bHi, acc[mf], 0, 0, 0);
        }
        // no trailing barrier: next iteration writes the other buffer
    }

    // epilogue: C/D layout col = l15, row = quad*4 + r; add bias, store fp32
    const int n = n0 + wn + l15;
    const float bv = bias[n];
    #pragma unroll
    for (int mf = 0; mf < 4; mf++) {
        #pragma unroll
        for (int r = 0; r < 4; r++) {
            int m = mf * 16 + quad * 4 + r;
            params[(size_t)m * TOTAL + n] = acc[mf][r] + bv;
        }
    }
}

// ---------------------------------------------------------------------------
// K2a v3: fc1 gate/value l2norm along D (64), write transposed bf16 WT[h][d].
// Single params read (bias already added by K1). grid 1024, block 256.
// ---------------------------------------------------------------------------
__global__ __launch_bounds__(256) void k2_fc1(
    const float* __restrict__ params, __bf16* __restrict__ WgT, __bf16* __restrict__ WvT)
{
    const int b    = blockIdx.x >> 4;
    const int mat  = (blockIdx.x >> 3) & 1;
    const int hg   = blockIdx.x & 7;
    const int t    = threadIdx.x;
    const int hh   = t & 31;        // h within group of 32
    const int dseg = t >> 5;        // 0..7, covers d = dseg*8..+7
    const int h    = hg * 32 + hh;

    __shared__ float psum[8 * 32];
    __shared__ float rnorm[32];

    const float* p0 = params + (size_t)b * TOTAL + mat * MAT_ELEMS;

    float val[8];
    float ss = 0.f;
    #pragma unroll
    for (int j = 0; j < 8; j++) {
        int off = (dseg * 8 + j) * 256 + h;
        float v = p0[off];
        val[j] = v;
        ss += v * v;
    }
    psum[dseg * 32 + hh] = ss;
    __syncthreads();
    if (t < 32) {
        float s2 = 0.f;
        #pragma unroll
        for (int g = 0; g < 8; g++) s2 += psum[g * 32 + t];
        rnorm[t] = 1.0f / fmaxf(sqrtf(s2), 1e-12f);
    }
    __syncthreads();
    float rn = rnorm[hh];
    __bf16* dst = (mat ? WvT : WgT) + (size_t)b * MAT_ELEMS + (size_t)h * 64 + dseg * 8;
    bf16x8 ov;
    #pragma unroll
    for (int j = 0; j < 8; j++) ov[j] = (__bf16)(val[j] * rn);
    *(bf16x8*)dst = ov;
}

// ---------------------------------------------------------------------------
// K2b v3: fc2 l2norm along H (256), write transposed bf16 WfT[d][h].
// Single params read. grid 512, block 256.
// ---------------------------------------------------------------------------
__global__ __launch_bounds__(256) void k2_fc2(
    const float* __restrict__ params, __bf16* __restrict__ WfT)
{
    const int b    = blockIdx.x >> 3;
    const int dg   = blockIdx.x & 7;
    const int t    = threadIdx.x;
    const int dd   = t & 7;         // d within group of 8
    const int hseg = t >> 3;        // 0..31, covers h = hseg*8..+7

    __shared__ float psum[32 * 8];
    __shared__ float rnorm[8];

    const float* p0 = params + (size_t)b * TOTAL + 2 * MAT_ELEMS;

    float val[8];
    float ss = 0.f;
    #pragma unroll
    for (int j = 0; j < 8; j++) {
        int off = (hseg * 8 + j) * 64 + dg * 8 + dd;
        float v = p0[off];
        val[j] = v;
        ss += v * v;
    }
    psum[hseg * 8 + dd] = ss;
    __syncthreads();
    if (t < 8) {
        float s2 = 0.f;
        #pragma unroll
        for (int g = 0; g < 32; g++) s2 += psum[g * 8 + t];
        rnorm[t] = 1.0f / fmaxf(sqrtf(s2), 1e-12f);
    }
    __syncthreads();
    float rn = rnorm[dd];
    __bf16* dst = WfT + (size_t)b * MAT_ELEMS + (size_t)(dg * 8 + dd) * 256 + hseg * 8;
    bf16x8 ov;
    #pragma unroll
    for (int j = 0; j < 8; j++) ov[j] = (__bf16)(val[j] * rn);
    *(bf16x8*)dst = ov;
}

// ---------------------------------------------------------------------------
// K3 v5: fused  xn = rmsnorm(x)*scale;  g = xn@Wg; v = xn@Wv; h = silu(g)*v;
//            out = h@Wf + x.
// Quarter(64h) granularity: hbuf [32][72] bf16 per wave = 18432 B/block ->
// LDS admits 8 blocks/CU.
// LAUNCH-BOUND HISTORY (the only thing this round changes):
//   (256,4) r3: VGPR 56, clean 160 MB traffic        <- natural allocation
//   (256,8) r4: VGPR 32, 880 MB scratch spill, 258us
//   (256,6) r5: VGPR 40, 551 MB scratch spill, 180us
// The allocator treats the min-waves arg as a hard budget and rounds DOWN;
// forcing >4 spills MFMA state. (256,4) is a MINIMUM guarantee, not a cap:
// natural 56 regs <= 64 means HW can still co-schedule 8 waves/SIMD now
// that LDS permits 8 blocks/CU. Do NOT raise this bound again.
// ---------------------------------------------------------------------------
__global__ __launch_bounds__(256, 4) void k3_fused(
    const float* __restrict__ x, const float* __restrict__ scale,
    const __bf16* __restrict__ WgT, const __bf16* __restrict__ WvT,
    const __bf16* __restrict__ WfT, float* __restrict__ out)
{
    const int b    = blockIdx.x >> 5;
    const int rb   = blockIdx.x & 31;
    const int t    = threadIdx.x;
    const int w    = t >> 6;
    const int lane = t & 63;
    const int l15  = lane & 15;
    const int quad = lane >> 4;

    __shared__ __bf16 h_sh[4 * 32 * 72];    // 18432 B: per-wave [32 rows][64h pad 72]

    const size_t row_base = ((size_t)b * NN + rb * 128) * DD;

    // per-lane scale slices for k = quad*8+j and 32+quad*8+j
    float sc[16];
    *(float4*)&sc[0]  = *(const float4*)&scale[quad * 8];
    *(float4*)&sc[4]  = *(const float4*)&scale[quad * 8 + 4];
    *(float4*)&sc[8]  = *(const float4*)&scale[32 + quad * 8];
    *(float4*)&sc[12] = *(const float4*)&scale[32 + quad * 8 + 4];

    // ---- phase 0: build A-fragments straight from global ----
    bf16x8 afrag[2][2];
    #pragma unroll
    for (int mt = 0; mt < 2; mt++) {
        int row = w * 32 + mt * 16 + l15;
        const float* xp = &x[row_base + (size_t)row * DD + quad * 8];
        float v[16];
        *(float4*)&v[0]  = *(const float4*)(xp);
        *(float4*)&v[4]  = *(const float4*)(xp + 4);
        *(float4*)&v[8]  = *(const float4*)(xp + 32);
        *(float4*)&v[12] = *(const float4*)(xp + 36);
        float ss = 0.f;
        #pragma unroll
        for (int j = 0; j < 16; j++) ss += v[j] * v[j];
        ss += __shfl_xor(ss, 16, 64);
        ss += __shfl_xor(ss, 32, 64);
        float rr = rsqrtf(ss * (1.0f / 64.0f) + 1e-6f);
        #pragma unroll
        for (int j = 0; j < 8; j++) {
            afrag[mt][0][j] = (__bf16)(v[j] * rr * sc[j]);
            afrag[mt][1][j] = (__bf16)(v[8 + j] * rr * sc[8 + j]);
        }
    }

    f32x4 oacc[2][4] = {};   // [mt][dt]
    const __bf16* wg_b = WgT + (size_t)b * MAT_ELEMS;
    const __bf16* wv_b = WvT + (size_t)b * MAT_ELEMS;
    const __bf16* wf_b = WfT + (size_t)b * MAT_ELEMS;
    __bf16* hbuf = &h_sh[w * 32 * 72];

    for (int qtr = 0; qtr < 4; qtr++) {
        // ============ fc1 phase: 2 np iterations, write-only LDS ===========
        #pragma unroll
        for (int npl = 0; npl < 2; npl++) {
            const int np = qtr * 2 + npl;
            // batch-issue all 8 weight fragment loads
            bf16x8 bg[2][2], bv[2][2];
            #pragma unroll
            for (int sub = 0; sub < 2; sub++) {
                int nt = np * 2 + sub;
                const __bf16* gp = &wg_b[(nt * 16 + l15) * 64 + quad * 8];
                const __bf16* vp = &wv_b[(nt * 16 + l15) * 64 + quad * 8];
                bg[sub][0] = *(const bf16x8*)(gp);
                bg[sub][1] = *(const bf16x8*)(gp + 32);
                bv[sub][0] = *(const bf16x8*)(vp);
                bv[sub][1] = *(const bf16x8*)(vp + 32);
            }
            #pragma unroll
            for (int sub = 0; sub < 2; sub++) {
                #pragma unroll
                for (int mt = 0; mt < 2; mt++) {
                    f32x4 g = {0.f, 0.f, 0.f, 0.f}, vv = {0.f, 0.f, 0.f, 0.f};
                    g  = __builtin_amdgcn_mfma_f32_16x16x32_bf16(afrag[mt][0], bg[sub][0], g, 0, 0, 0);
                    g  = __builtin_amdgcn_mfma_f32_16x16x32_bf16(afrag[mt][1], bg[sub][1], g, 0, 0, 0);
                    vv = __builtin_amdgcn_mfma_f32_16x16x32_bf16(afrag[mt][0], bv[sub][0], vv, 0, 0, 0);
                    vv = __builtin_amdgcn_mfma_f32_16x16x32_bf16(afrag[mt][1], bv[sub][1], vv, 0, 0, 0);
                    #pragma unroll
                    for (int r = 0; r < 4; r++) {
                        float gv = g[r];
                        float sig = __builtin_amdgcn_rcpf(1.0f + __expf(-gv));
                        float hval = gv * sig * vv[r];
                        hbuf[(mt * 16 + quad * 4 + r) * 72 + npl * 32 + sub * 16 + l15] = (__bf16)hval;
                    }
                }
            }
        }
        // ============ fc2 phase: sweep the 64-h quarter ====================
        #pragma unroll
        for (int kpl = 0; kpl < 2; kpl++) {
            const int kp = qtr * 2 + kpl;
            bf16x8 bf[4];
            #pragma unroll
            for (int dt = 0; dt < 4; dt++)
                bf[dt] = *(const bf16x8*)&wf_b[(dt * 16 + l15) * 256 + kp * 32 + quad * 8];
            #pragma unroll
            for (int mt = 0; mt < 2; mt++) {
                bf16x8 ah = *(const bf16x8*)&hbuf[(mt * 16 + l15) * 72 + kpl * 32 + quad * 8];
                #pragma unroll
                for (int dt = 0; dt < 4; dt++)
                    oacc[mt][dt] = __builtin_amdgcn_mfma_f32_16x16x32_bf16(ah, bf[dt], oacc[mt][dt], 0, 0, 0);
            }
        }
    }

    // ---- epilogue: += x residual (cache-hot), store fp32 (C-layout) ----
    #pragma unroll
    for (int mt = 0; mt < 2; mt++) {
        int r0 = w * 32 + mt * 16 + quad * 4;
        #pragma unroll
        for (int rg = 0; rg < 4; rg++) {
            size_t roff = row_base + (size_t)(r0 + rg) * DD;
            #pragma unroll
            for (int dt = 0; dt < 4; dt++) {
                int col = dt * 16 + l15;
                out[roff + col] = oacc[mt][dt][rg] + x[roff + col];
            }
        }
    }
}

// ---------------------------------------------------------------------------
extern "C" void kernel_launch(void* const* d_in, const int* in_sizes, int n_in,
                              void* d_out, int out_size, void* d_ws, size_t ws_size,
                              hipStream_t stream)
{
    const float* x     = (const float*)d_in[0];
    const float* s     = (const float*)d_in[1];
    const float* W_pg  = (const float*)d_in[2];
    const float* b_pg  = (const float*)d_in[3];
    const float* scale = (const float*)d_in[4];
    float* out = (float*)d_out;

    char* ws = (char*)d_ws;
    float*  params = (float*)ws;                                  // 12,582,912 B
    __bf16* WgT    = (__bf16*)(ws + 12582912);                    //  2,097,152 B
    __bf16* WvT    = (__bf16*)(ws + 14680064);                    //  2,097,152 B
    __bf16* WfT    = (__bf16*)(ws + 16777216);                    //  2,097,152 B
    __bf16* sHi    = (__bf16*)(ws + 18874368);                    //    131,072 B
    __bf16* sLo    = (__bf16*)(ws + 19005440);                    //    131,072 B

    k0_sconv<<<32, 256, 0, stream>>>(s, sHi, sLo);
    k1_gemm<<<TOTAL / 64, 256, 0, stream>>>(sHi, sLo, W_pg, b_pg, params);
    k2_fc1<<<BB * 16, 256, 0, stream>>>(params, WgT, WvT);
    k2_fc2<<<BB * 8, 256, 0, stream>>>(params, WfT);
    k3_fused<<<BB * 32, 256, 0, stream>>>(x, scale, WgT, WvT, WfT, out);
}